// Round 3
// baseline (333.550 us; speedup 1.0000x reference)
//
#include <hip/hip_runtime.h>

// Shapes (fixed by the reference):
//   x:  (N=32, C=384, H=56, W=56)  -> (n, c, p) with HW=3136 = 49*64
//   gf: (N=32, M=8, D=768)
//   W_kv: (E=768, D=768), b_kv: (768,)
//   kv[n][m][e] = clip(sum_d gf[n][m][d]*W[e][d] + b[e], 0, 6)
//   K = kv[..., :384], V = kv[..., 384:]
//   scores[n,p,k] = sum_c x[n,c,p]*K[n,k,c]; attn = softmax_k
//   out[n,c,p] = x[n,c,p] + sum_k attn[n,p,k]*V[n,k,c]

#define NC 384
#define HWP 3136
#define DD 768
#define MM 8
#define EE 768

// ---------------- Kernel 1: KV projection + ReLU6 ----------------
// grid (12, 32), block 256. Block = one n, 64 e's, all 8 m's (2 m's/thread).
__global__ __launch_bounds__(256) void kv_kernel(const float* __restrict__ gf,
                                                 const float* __restrict__ Wk,
                                                 const float* __restrict__ bk,
                                                 float* __restrict__ kv) {
    __shared__ float g[MM * DD];  // 24 KB
    const int n = blockIdx.y;
    const int et = blockIdx.x;   // 0..11
    const int t = threadIdx.x;

    const float* gfn = gf + (size_t)n * (MM * DD);
    for (int i = t; i < MM * DD; i += 256) g[i] = gfn[i];
    __syncthreads();

    const int e = et * 64 + (t & 63);
    const int mb = (t >> 6) * 2;  // wave-uniform m pair

    const float4* w4 = (const float4*)(Wk + (size_t)e * DD);
    const float4* g0 = (const float4*)(g + (mb + 0) * DD);
    const float4* g1 = (const float4*)(g + (mb + 1) * DD);

    float a0 = 0.f, a1 = 0.f;
    #pragma unroll 8
    for (int i = 0; i < DD / 4; ++i) {
        const float4 w = w4[i];
        const float4 v0 = g0[i];
        const float4 v1 = g1[i];
        a0 += w.x * v0.x + w.y * v0.y + w.z * v0.z + w.w * v0.w;
        a1 += w.x * v1.x + w.y * v1.y + w.z * v1.z + w.w * v1.w;
    }
    const float bv = bk[e];
    float* o = kv + (size_t)n * (MM * EE);
    o[(mb + 0) * EE + e] = fminf(fmaxf(a0 + bv, 0.f), 6.f);
    o[(mb + 1) * EE + e] = fminf(fmaxf(a1 + bv, 0.f), 6.f);
}

// ---------------- Kernel 2: fused attention + residual ----------------
// grid (49, 32), block 256 = 4 waves. Block = (n, 64 positions); wave w owns
// positions [tile*64 + w*16, +16) and ALL 384 channels:
//   lane = (q = lane&3: position quad -> float4 global access,
//           g = lane>>2: one of 16 24-channel groups).
// Score reduce = in-wave shfl_xor butterfly over lane bits 2..5.
// Softmax per-lane in registers. ONE barrier total (kv staging).
// K/V in LDS with 25-float group stride: 16 distinct g -> 16 distinct banks.
__global__ __launch_bounds__(256) void attn_kernel(const float* __restrict__ x,
                                                   const float* __restrict__ kv,
                                                   float* __restrict__ out) {
    // K: [k]*400 + g*25 + j (j<24);  V: 3200 + same.  25.6 KB
    __shared__ float kvs[6400];

    const int n = blockIdx.y;
    const int tile = blockIdx.x;        // 0..48
    const int t = threadIdx.x;
    const int lane = t & 63;
    const int w = t >> 6;
    const int q = lane & 3;             // position quad
    const int g = lane >> 2;            // channel group (0..15)
    const int c0 = g * 24;
    const int pos0 = tile * 64 + w * 16 + q * 4;

    // stage this n's K and V into the padded layout (coalesced global reads)
    const float* kvn = kv + (size_t)n * (MM * EE);
    for (int idx = t; idx < MM * EE; idx += 256) {
        const int k = idx / EE;
        const int e = idx - k * EE;
        const int half = (e >= 384) ? 1 : 0;
        const int c = e - half * 384;
        const int gg = c / 24;
        const int j = c - gg * 24;
        kvs[half * 3200 + k * 400 + gg * 25 + j] = kvn[idx];
    }

    // load my 24 channels x 4 positions of x (float4, 16B/lane)
    const float* xp = x + (size_t)n * NC * HWP + (size_t)c0 * HWP + pos0;
    float4 xr[24];
    #pragma unroll
    for (int i = 0; i < 24; ++i) xr[i] = *(const float4*)(xp + (size_t)i * HWP);

    __syncthreads();  // the only barrier

    // partial scores over my 24 channels (conflict-free scalar LDS reads)
    float acc[8][4];
    #pragma unroll
    for (int k = 0; k < 8; ++k)
        #pragma unroll
        for (int j = 0; j < 4; ++j) acc[k][j] = 0.f;

    #pragma unroll
    for (int i = 0; i < 24; ++i) {
        const float4 xv = xr[i];
        #pragma unroll
        for (int k = 0; k < 8; ++k) {
            const float kc = kvs[k * 400 + g * 25 + i];
            acc[k][0] += xv.x * kc;
            acc[k][1] += xv.y * kc;
            acc[k][2] += xv.z * kc;
            acc[k][3] += xv.w * kc;
        }
    }

    // butterfly-reduce across the 16 channel groups (lane bits 2..5);
    // afterwards every lane holds the FULL score for its quad's positions
    #pragma unroll
    for (int k = 0; k < 8; ++k) {
        #pragma unroll
        for (int j = 0; j < 4; ++j) {
            float v = acc[k][j];
            v += __shfl_xor(v, 4, 64);
            v += __shfl_xor(v, 8, 64);
            v += __shfl_xor(v, 16, 64);
            v += __shfl_xor(v, 32, 64);
            acc[k][j] = v;
        }
    }

    // per-lane softmax over the 8 keys for my 4 positions (no LDS, no barrier)
    float aw[8][4];
    #pragma unroll
    for (int j = 0; j < 4; ++j) {
        float mx = acc[0][j];
        #pragma unroll
        for (int k = 1; k < 8; ++k) mx = fmaxf(mx, acc[k][j]);
        float sum = 0.f;
        #pragma unroll
        for (int k = 0; k < 8; ++k) {
            const float e = __expf(acc[k][j] - mx);
            aw[k][j] = e;
            sum += e;
        }
        const float inv = 1.f / sum;
        #pragma unroll
        for (int k = 0; k < 8; ++k) aw[k][j] *= inv;
    }

    // output: out = x + sum_k aw[k]*V[k][c], float4 stores
    float* op = out + (size_t)n * NC * HWP + (size_t)c0 * HWP + pos0;
    #pragma unroll
    for (int i = 0; i < 24; ++i) {
        float4 o = xr[i];
        #pragma unroll
        for (int k = 0; k < 8; ++k) {
            const float v = kvs[3200 + k * 400 + g * 25 + i];
            o.x += aw[k][0] * v;
            o.y += aw[k][1] * v;
            o.z += aw[k][2] * v;
            o.w += aw[k][3] * v;
        }
        *(float4*)(op + (size_t)i * HWP) = o;
    }
}

extern "C" void kernel_launch(void* const* d_in, const int* in_sizes, int n_in,
                              void* d_out, int out_size, void* d_ws, size_t ws_size,
                              hipStream_t stream) {
    const float* x  = (const float*)d_in[0];
    const float* gf = (const float*)d_in[1];
    const float* Wk = (const float*)d_in[2];
    const float* bk = (const float*)d_in[3];
    float* out = (float*)d_out;
    float* kv = (float*)d_ws;  // 32*8*768 floats = 768 KB

    kv_kernel<<<dim3(12, 32), 256, 0, stream>>>(gf, Wk, bk, kv);
    attn_kernel<<<dim3(49, 32), 256, 0, stream>>>(x, kv, out);
}

// Round 4
// 319.707 us; speedup vs baseline: 1.0433x; 1.0433x over previous
//
#include <hip/hip_runtime.h>

// Shapes (fixed by the reference):
//   x:  (N=32, C=384, H=56, W=56)  -> (n, c, p) with HW=3136 = 98*32
//   gf: (N=32, M=8, D=768)
//   W_kv: (E=768, D=768), b_kv: (768,)
//   kv[n][m][e] = clip(sum_d gf[n][m][d]*W[e][d] + b[e], 0, 6)
//   K = kv[..., :384], V = kv[..., 384:]
//   scores[n,p,k] = sum_c x[n,c,p]*K[n,k,c]; attn = softmax_k
//   out[n,c,p] = x[n,c,p] + sum_k attn[n,p,k]*V[n,k,c]

#define NC 384
#define HWP 3136
#define DD 768
#define MM 8
#define EE 768

// ---------------- Kernel 1: KV projection + ReLU6 ----------------
// grid (12, 32), block 256. Block = one n, 64 e's, all 8 m's (2 m's/thread).
__global__ __launch_bounds__(256) void kv_kernel(const float* __restrict__ gf,
                                                 const float* __restrict__ Wk,
                                                 const float* __restrict__ bk,
                                                 float* __restrict__ kv) {
    __shared__ float g[MM * DD];  // 24 KB
    const int n = blockIdx.y;
    const int et = blockIdx.x;   // 0..11
    const int t = threadIdx.x;

    const float* gfn = gf + (size_t)n * (MM * DD);
    for (int i = t; i < MM * DD; i += 256) g[i] = gfn[i];
    __syncthreads();

    const int e = et * 64 + (t & 63);
    const int mb = (t >> 6) * 2;  // wave-uniform m pair

    const float4* w4 = (const float4*)(Wk + (size_t)e * DD);
    const float4* g0 = (const float4*)(g + (mb + 0) * DD);
    const float4* g1 = (const float4*)(g + (mb + 1) * DD);

    float a0 = 0.f, a1 = 0.f;
    #pragma unroll 8
    for (int i = 0; i < DD / 4; ++i) {
        const float4 w = w4[i];
        const float4 v0 = g0[i];
        const float4 v1 = g1[i];
        a0 += w.x * v0.x + w.y * v0.y + w.z * v0.z + w.w * v0.w;
        a1 += w.x * v1.x + w.y * v1.y + w.z * v1.z + w.w * v1.w;
    }
    const float bv = bk[e];
    float* o = kv + (size_t)n * (MM * EE);
    o[(mb + 0) * EE + e] = fminf(fmaxf(a0 + bv, 0.f), 6.f);
    o[(mb + 1) * EE + e] = fminf(fmaxf(a1 + bv, 0.f), 6.f);
}

// ---------------- Kernel 2: fused attention + residual ----------------
// grid (98, 32), block 256 = 4 waves. Block = (n, 32 positions).
// Thread = (p2 = t&15: pair of consecutive positions -> float2 global access;
//           gq = t>>4: one of 16 24-channel groups).
// Per-wave global segments: 16 consecutive lanes x 8B = 128B (full lines).
// xr = 24 float2 = 48 VGPRs -> stays live through the epilogue (no x re-read).
// Score reduce: shfl_xor over lane bits 4,5 (in-wave groups) + one LDS pass
// for cross-wave; softmax computed redundantly per-thread (no 3rd barrier).
// kv LDS layout: group stride 28 words (4-aligned; banks >=16 distinct).
__global__ __launch_bounds__(256, 4) void attn_kernel(const float* __restrict__ x,
                                                      const float* __restrict__ kv,
                                                      float* __restrict__ out) {
    __shared__ float kvs[7168];     // 28 KB: [half][k*448 + g*28 + j], j<24
    __shared__ float sc[4][8][32];  // 4 KB: per-wave partial scores [w][k][pos]

    const int n = blockIdx.y;
    const int tile = blockIdx.x;     // 0..97
    const int t = threadIdx.x;
    const int p2 = t & 15;           // position pair
    const int gq = t >> 4;           // channel group (0..15)
    const int w = t >> 6;            // wave
    const int c0 = gq * 24;
    const int pos0 = tile * 32 + p2 * 2;

    // stage this n's K/V into padded layout (float4 global + float4 LDS writes)
    const float4* kvn4 = (const float4*)(kv + (size_t)n * (MM * EE));
    #pragma unroll
    for (int r = 0; r < 6; ++r) {
        const int f = t + r * 256;        // float4 index 0..1535
        const int k = f / 192;
        const int e4 = f - k * 192;       // 0..191
        const int half = (e4 >= 96) ? 1 : 0;
        const int c4 = e4 - half * 96;    // 0..95
        const int g = c4 / 6;
        const int j4 = c4 - g * 6;
        *(float4*)&kvs[half * 3584 + k * 448 + g * 28 + j4 * 4] = kvn4[f];
    }

    // load my 24 channels x 2 positions of x (float2, 8B/lane, 128B segments)
    const float* xp = x + (size_t)n * NC * HWP + (size_t)c0 * HWP + pos0;
    float2 xr[24];
    #pragma unroll
    for (int i = 0; i < 24; ++i) xr[i] = *(const float2*)(xp + (size_t)i * HWP);

    __syncthreads();

    // partial scores over my 24 channels (K as float4 LDS reads)
    float accx[8], accy[8];
    #pragma unroll
    for (int k = 0; k < 8; ++k) { accx[k] = 0.f; accy[k] = 0.f; }

    #pragma unroll
    for (int i4 = 0; i4 < 6; ++i4) {
        const float2 x0 = xr[i4 * 4 + 0];
        const float2 x1 = xr[i4 * 4 + 1];
        const float2 x2 = xr[i4 * 4 + 2];
        const float2 x3 = xr[i4 * 4 + 3];
        #pragma unroll
        for (int k = 0; k < 8; ++k) {
            const float4 kk = *(const float4*)&kvs[k * 448 + gq * 28 + i4 * 4];
            accx[k] += x0.x * kk.x + x1.x * kk.y + x2.x * kk.z + x3.x * kk.w;
            accy[k] += x0.y * kk.x + x1.y * kk.y + x2.y * kk.z + x3.y * kk.w;
        }
    }

    // in-wave reduce across the wave's 4 channel groups (lane bits 4,5)
    #pragma unroll
    for (int k = 0; k < 8; ++k) {
        accx[k] += __shfl_xor(accx[k], 16, 64);
        accx[k] += __shfl_xor(accx[k], 32, 64);
        accy[k] += __shfl_xor(accy[k], 16, 64);
        accy[k] += __shfl_xor(accy[k], 32, 64);
    }
    if ((t & 48) == 0) {  // lanes 0..15 of each wave hold the wave-partials
        #pragma unroll
        for (int k = 0; k < 8; ++k)
            *(float2*)&sc[w][k][p2 * 2] = make_float2(accx[k], accy[k]);
    }
    __syncthreads();

    // every thread: sum the 4 wave-partials for its 2 positions, softmax over k
    float sx[8], sy[8];
    #pragma unroll
    for (int k = 0; k < 8; ++k) {
        float2 s = *(const float2*)&sc[0][k][p2 * 2];
        #pragma unroll
        for (int ww = 1; ww < 4; ++ww) {
            const float2 q = *(const float2*)&sc[ww][k][p2 * 2];
            s.x += q.x; s.y += q.y;
        }
        sx[k] = s.x; sy[k] = s.y;
    }
    {
        float mx = sx[0], my = sy[0];
        #pragma unroll
        for (int k = 1; k < 8; ++k) { mx = fmaxf(mx, sx[k]); my = fmaxf(my, sy[k]); }
        float sux = 0.f, suy = 0.f;
        #pragma unroll
        for (int k = 0; k < 8; ++k) {
            sx[k] = __expf(sx[k] - mx); sux += sx[k];
            sy[k] = __expf(sy[k] - my); suy += sy[k];
        }
        const float ix = 1.f / sux, iy = 1.f / suy;
        #pragma unroll
        for (int k = 0; k < 8; ++k) { sx[k] *= ix; sy[k] *= iy; }
    }

    // epilogue: out = x + sum_k aw[k]*V[k][c]; xr is live, no x re-read
    float* op = out + (size_t)n * NC * HWP + (size_t)c0 * HWP + pos0;
    #pragma unroll
    for (int i4 = 0; i4 < 6; ++i4) {
        float2 o0 = xr[i4 * 4 + 0];
        float2 o1 = xr[i4 * 4 + 1];
        float2 o2 = xr[i4 * 4 + 2];
        float2 o3 = xr[i4 * 4 + 3];
        #pragma unroll
        for (int k = 0; k < 8; ++k) {
            const float4 vv = *(const float4*)&kvs[3584 + k * 448 + gq * 28 + i4 * 4];
            o0.x += sx[k] * vv.x; o0.y += sy[k] * vv.x;
            o1.x += sx[k] * vv.y; o1.y += sy[k] * vv.y;
            o2.x += sx[k] * vv.z; o2.y += sy[k] * vv.z;
            o3.x += sx[k] * vv.w; o3.y += sy[k] * vv.w;
        }
        *(float2*)(op + (size_t)(i4 * 4 + 0) * HWP) = o0;
        *(float2*)(op + (size_t)(i4 * 4 + 1) * HWP) = o1;
        *(float2*)(op + (size_t)(i4 * 4 + 2) * HWP) = o2;
        *(float2*)(op + (size_t)(i4 * 4 + 3) * HWP) = o3;
    }
}

extern "C" void kernel_launch(void* const* d_in, const int* in_sizes, int n_in,
                              void* d_out, int out_size, void* d_ws, size_t ws_size,
                              hipStream_t stream) {
    const float* x  = (const float*)d_in[0];
    const float* gf = (const float*)d_in[1];
    const float* Wk = (const float*)d_in[2];
    const float* bk = (const float*)d_in[3];
    float* out = (float*)d_out;
    float* kv = (float*)d_ws;  // 32*8*768 floats = 768 KB

    kv_kernel<<<dim3(12, 32), 256, 0, stream>>>(gf, Wk, bk, kv);
    attn_kernel<<<dim3(98, 32), 256, 0, stream>>>(x, kv, out);
}